// Round 5
// baseline (65.614 us; speedup 1.0000x reference)
//
#include <hip/hip_runtime.h>

#define B_ 2
#define C_ 121
#define H_ 128
#define W_ 256
#define D_ 48
#define NT 256       // 4 waves: 64 w-quads x 4 d-groups
#define NDY 4        // disparities per thread
#define ZS 3         // d-split: 16 d per block

typedef float f32x4 __attribute__((ext_vector_type(4)));

__launch_bounds__(NT)
__global__ void cost_volume_kernel(const float* __restrict__ xg,
                                   const float* __restrict__ yg,
                                   float* __restrict__ out)
{
    const int t  = threadIdx.x;
    const int h  = blockIdx.x;
    const int b  = blockIdx.y;
    const int z  = blockIdx.z;          // owns d in [z*16, z*16+16)
    const int wq = t & 63;              // w-quad: w = wq*4 .. wq*4+3
    const int wv = t >> 6;              // wave id = d-group, 0..3
    const int d0 = z * 16 + wv * NDY;   // multiple of 4
    const int w0 = wq * 4;

    // y window: needed global w-index = w0+jw - (d0+jd) = g0 + (4+jw-jd),
    // g0 = w0-d0-4 (multiple of 4, range [-48,248]). Negative-start quads feed
    // only masked (w<d) outputs, so clamp each aligned quad's start to >= 0.
    const int g0 = w0 - d0 - 4;
    const int gA = g0     > 0 ? g0     : 0;
    const int gB = g0 + 4 > 0 ? g0 + 4 : 0;

    const size_t row0 = (((size_t)b * C_) * H_ + h) * (size_t)W_;  // c=0 row
    const float* xp = xg + row0 + w0;
    const float* pA = yg + row0 + gA;
    const float* pB = yg + row0 + gB;

    constexpr int HW = H_ * W_;

    float acc[NDY][4];
    #pragma unroll
    for (int jd = 0; jd < NDY; ++jd)
        #pragma unroll
        for (int jw = 0; jw < 4; ++jw) acc[jd][jw] = 0.0f;

    int co = 0;                          // uniform channel offset c*HW
    for (int k = 0; k < 11; ++k) {
        #pragma unroll
        for (int cc = 0; cc < 11; ++cc) {
            const f32x4 xv = *(const f32x4*)(xp + co);
            float yw[8];
            *(f32x4*)&yw[0] = *(const f32x4*)(pA + co);
            *(f32x4*)&yw[4] = *(const f32x4*)(pB + co);
            co += HW;

            const float xvv[4] = {xv.x, xv.y, xv.z, xv.w};
            #pragma unroll
            for (int jd = 0; jd < NDY; ++jd)
                #pragma unroll
                for (int jw = 0; jw < 4; ++jw)
                    acc[jd][jw] += __builtin_fabsf(xvv[jw] - yw[4 + jw - jd]);

            // prefix boundaries: c+1 = kk^2, kk=3..11. cc is constant here, so
            // (k*11+cc == bc) folds to a single scalar k==const (or false).
            #pragma unroll
            for (int bi = 0; bi < 9; ++bi) {
                constexpr int KB[9] = {8, 15, 24, 35, 48, 63, 80, 99, 120};
                const int bc = KB[bi];
                if (k * 11 + cc == bc) {
                    const float inv = 1.0f / (float)(bc + 1);
                    const size_t obase = (((size_t)b * 9 + bi) * D_) * (size_t)HW
                                       + (size_t)h * W_ + (size_t)w0;
                    #pragma unroll
                    for (int jd = 0; jd < NDY; ++jd) {
                        const int d = d0 + jd;
                        f32x4 v;
                        v.x = (w0 + 0 >= d) ? acc[jd][0] * inv : 0.0f;
                        v.y = (w0 + 1 >= d) ? acc[jd][1] * inv : 0.0f;
                        v.z = (w0 + 2 >= d) ? acc[jd][2] * inv : 0.0f;
                        v.w = (w0 + 3 >= d) ? acc[jd][3] * inv : 0.0f;
                        __builtin_nontemporal_store(v,
                            (f32x4*)&out[obase + (size_t)d * HW]);
                    }
                }
            }
        }
    }
}

extern "C" void kernel_launch(void* const* d_in, const int* in_sizes, int n_in,
                              void* d_out, int out_size, void* d_ws, size_t ws_size,
                              hipStream_t stream)
{
    const float* x = (const float*)d_in[0];
    const float* y = (const float*)d_in[1];
    float* o = (float*)d_out;
    dim3 grid(H_, B_, ZS);   // z slowest: d-split siblings 256 ids apart -> same XCD, shared rows
    dim3 block(NT, 1, 1);
    hipLaunchKernelGGL(cost_volume_kernel, grid, block, 0, stream, x, y, o);
}

// Round 6
// 55.893 us; speedup vs baseline: 1.1739x; 1.1739x over previous
//
#include <hip/hip_runtime.h>

#define B_ 2
#define C_ 121
#define H_ 128
#define W_ 256
#define D_ 48
#define CT 11        // channels per LDS chunk
#define NCHUNK 11    // 121 = 11 * 11
#define NT 256       // 4 waves: 64 w-quads x 4 d-groups
#define NDY 4        // disparities per thread
#define YROW 312     // padded y row (need 304); 1248B stride rotates bank start by 24
#define ZS 3         // d-split: 16 d per block

typedef float f32x4 __attribute__((ext_vector_type(4)));
typedef const void __attribute__((address_space(1)))* gas1_t;
typedef void __attribute__((address_space(3)))* las3_t;

__launch_bounds__(NT)
__global__ void cost_volume_kernel(const float* __restrict__ xg,
                                   const float* __restrict__ yg,
                                   float* __restrict__ out)
{
    // Only Y is staged: [chunk-channel][p], p = w' + 48, w' in [-48,256); p<48 zero pad.
    __shared__ __align__(16) float YLS[2][CT][YROW];

    const int t  = threadIdx.x;
    const int h  = blockIdx.x;
    const int b  = blockIdx.y;
    const int z  = blockIdx.z;          // owns d in [z*16, z*16+16)
    const int wq = t & 63;              // w-quad: w = wq*4 .. wq*4+3
    const int wv = t >> 6;              // wave id = d-group, 0..3
    const int d0 = z * 16 + wv * NDY;   // multiple of 4
    const int w0 = wq * 4;

    // zero the left pad (p in [0,48)) of every y row, both buffers, once.
    for (int i = t; i < 2 * CT * 48; i += NT) {
        int nb = i / (CT * 48);
        int r  = i % (CT * 48);
        YLS[nb][r / 48][r % 48] = 0.0f;
    }

    constexpr int HW = H_ * W_;
    const size_t row0 = (((size_t)b * C_) * H_ + h) * (size_t)W_;  // c=0 row
    const float* xp = xg + row0 + w0;

    // stage one chunk of Y rows (11) directly global->LDS (async prefetch).
    auto stage = [&](int chunk, int nb) {
        for (int i = wv; i < CT; i += 4) {   // wave-uniform loop
            const int c = chunk * CT + i;
            __builtin_amdgcn_global_load_lds(
                (gas1_t)(yg + row0 + (size_t)c * HW + (size_t)wq * 4),
                (las3_t)&YLS[nb][i][48], 16, 0, 0);
        }
    };

    float acc[NDY][4];
    #pragma unroll
    for (int jd = 0; jd < NDY; ++jd)
        #pragma unroll
        for (int jw = 0; jw < 4; ++jw) acc[jd][jw] = 0.0f;

    stage(0, 0);
    __syncthreads();

    // y window: needed p = w0+jw-(d0+jd)+48 = bp + (4+jw-jd), idx in [1,7];
    // bp = w0-d0+44 is a multiple of 4, bp+7 <= 303 < YROW.
    const int bp = w0 - d0 + 44;

    for (int k = 0; k < NCHUNK; ++k) {
        const int cur = k & 1;

        // batch-load this chunk's 11 x quads into registers (independent
        // loads, issued together -> L1/L2 latency fully overlapped).
        f32x4 xq[CT];
        #pragma unroll
        for (int cc = 0; cc < CT; ++cc)
            xq[cc] = *(const f32x4*)(xp + (size_t)(k * CT + cc) * HW);

        if (k + 1 < NCHUNK) stage(k + 1, cur ^ 1);   // async prefetch next chunk

        #pragma unroll
        for (int cc = 0; cc < CT; ++cc) {
            float yw[8];
            *(f32x4*)&yw[0] = *(const f32x4*)&YLS[cur][cc][bp];
            *(f32x4*)&yw[4] = *(const f32x4*)&YLS[cur][cc][bp + 4];

            const float xvv[4] = {xq[cc].x, xq[cc].y, xq[cc].z, xq[cc].w};
            #pragma unroll
            for (int jd = 0; jd < NDY; ++jd)
                #pragma unroll
                for (int jw = 0; jw < 4; ++jw)
                    acc[jd][jw] += __builtin_fabsf(xvv[jw] - yw[4 + jw - jd]);

            // prefix boundaries: c+1 = kk^2, kk=3..11 (folds to scalar k==const)
            #pragma unroll
            for (int bi = 0; bi < 9; ++bi) {
                constexpr int KB[9] = {8, 15, 24, 35, 48, 63, 80, 99, 120};
                const int bc = KB[bi];
                if (k * CT + cc == bc) {
                    const float inv = 1.0f / (float)(bc + 1);
                    const size_t obase = (((size_t)b * 9 + bi) * D_) * (size_t)HW
                                       + (size_t)h * W_ + (size_t)w0;
                    #pragma unroll
                    for (int jd = 0; jd < NDY; ++jd) {
                        const int d = d0 + jd;
                        f32x4 v;
                        v.x = (w0 + 0 >= d) ? acc[jd][0] * inv : 0.0f;
                        v.y = (w0 + 1 >= d) ? acc[jd][1] * inv : 0.0f;
                        v.z = (w0 + 2 >= d) ? acc[jd][2] * inv : 0.0f;
                        v.w = (w0 + 3 >= d) ? acc[jd][3] * inv : 0.0f;
                        __builtin_nontemporal_store(v,
                            (f32x4*)&out[obase + (size_t)d * HW]);
                    }
                }
            }
        }
        __syncthreads();
    }
}

extern "C" void kernel_launch(void* const* d_in, const int* in_sizes, int n_in,
                              void* d_out, int out_size, void* d_ws, size_t ws_size,
                              hipStream_t stream)
{
    const float* x = (const float*)d_in[0];
    const float* y = (const float*)d_in[1];
    float* o = (float*)d_out;
    dim3 grid(H_, B_, ZS);   // z slowest: d-split siblings 256 ids apart -> same XCD
    dim3 block(NT, 1, 1);
    hipLaunchKernelGGL(cost_volume_kernel, grid, block, 0, stream, x, y, o);
}